// Round 2
// baseline (288.701 us; speedup 1.0000x reference)
//
#include <hip/hip_runtime.h>
#include <float.h>

// Problem constants
#define N_PTS    32768       // 8*16*16*16 spatial positions
#define N_CODES  2048
#define DIM      256
#define S_STRIDE 4096        // d*h*w stride of channel dim in z (floats)
#define B_STRIDE 1048576     // per-batch stride in z (256*4096 floats)
#define N_ELEM   8388608     // total z elements

#define MARGIN   8e-4f       // >= 2x |screen-score - np-score| bound (validated R5-R7)

// ws layout (bytes), 512-aligned
#define WS_PARTIAL 0          // float[64]
#define WS_E2      512        // float[2048]             -> 8704
#define WS_EB      8704       // bf16[2048*256] 1 MB     -> 1057280
#define WS_ZT      1057280    // bf16[32768*256] 16.8 MB -> 17834496
#define WS_TMIN    17834496   // float[32768*128] 16.8MB -> 34611712

typedef unsigned short ushort_t;
typedef short bf16x8 __attribute__((ext_vector_type(8)));
typedef float f32x4 __attribute__((ext_vector_type(4)));

__device__ __forceinline__ ushort_t f2bf(float v) {   // RNE fp32->bf16 (no NaN in data)
    const unsigned u = __float_as_uint(v);
    return (ushort_t)((u + 0x7FFFu + ((u >> 16) & 1u)) >> 16);
}

__device__ __forceinline__ void async_copy16(void* lds, const void* g) {
    __builtin_amdgcn_global_load_lds(
        (const __attribute__((address_space(1))) unsigned int*)g,
        (__attribute__((address_space(3))) unsigned int*)lds, 16, 0, 0);
}

// emb fp32 [k][256] -> bf16 eb [k][256] (coalesced)
__global__ void conv_emb_kernel(const float* __restrict__ emb, ushort_t* __restrict__ eb) {
    const int gid = blockIdx.x * 256 + threadIdx.x;   // 512 blocks: 2048 codes x 64 float4
    const int k = gid >> 6, c4 = gid & 63;
    const float4 u = *reinterpret_cast<const float4*>(emb + (size_t)k * DIM + c4 * 4);
    ushort4 v; v.x = f2bf(u.x); v.y = f2bf(u.y); v.z = f2bf(u.z); v.w = f2bf(u.w);
    *reinterpret_cast<ushort4*>(eb + (size_t)k * DIM + c4 * 4) = v;
}

// e2[k] = np-pairwise sum of emb[k][:]^2; also zeroes loss partials.
__global__ void e2p_kernel(const float* __restrict__ emb, float* __restrict__ e2,
                           float* __restrict__ partial) {
    const int k = blockIdx.x * 256 + threadIdx.x;
    if (blockIdx.x == 0 && threadIdx.x < 64) partial[threadIdx.x] = 0.f;
    const float* base = emb + (size_t)k * DIM;
    float half[2];
    #pragma unroll
    for (int h = 0; h < 2; ++h) {
        float r[8];
        #pragma unroll
        for (int j = 0; j < 8; ++j) { const float v = base[h * 128 + j]; r[j] = __fmul_rn(v, v); }
        for (int t = 8; t < 128; t += 8)
            #pragma unroll
            for (int j = 0; j < 8; ++j) {
                const float v = base[h * 128 + t + j];
                r[j] = __fadd_rn(r[j], __fmul_rn(v, v));
            }
        half[h] = __fadd_rn(__fadd_rn(__fadd_rn(r[0], r[1]), __fadd_rn(r[2], r[3])),
                            __fadd_rn(__fadd_rn(r[4], r[5]), __fadd_rn(r[6], r[7])));
    }
    e2[k] = __fadd_rn(half[0], half[1]);
}

// z [8][256][4096] fp32 -> z_t [n][c] bf16 (pitch 256), 64x64 LDS transpose tiles.
__global__ void transpose_kernel(const float* __restrict__ z, ushort_t* __restrict__ zt) {
    __shared__ ushort_t lt[64][72];
    const int bx = blockIdx.x;            // 2048 = 8 b x 4 cg x 64 sg
    const int b = bx >> 8, cg = (bx >> 6) & 3, sg = bx & 63;
    const int c0 = cg * 64, s0 = sg * 64;
    const int t = threadIdx.x;
    {
        const int cl = t >> 4, s4 = t & 15;
        #pragma unroll
        for (int j = 0; j < 4; ++j) {
            const int c = cl + 16 * j;
            const float4 u = *reinterpret_cast<const float4*>(
                z + (size_t)b * B_STRIDE + (size_t)(c0 + c) * S_STRIDE + s0 + s4 * 4);
            ushort4 v; v.x = f2bf(u.x); v.y = f2bf(u.y); v.z = f2bf(u.z); v.w = f2bf(u.w);
            *reinterpret_cast<ushort4*>(&lt[c][s4 * 4]) = v;
        }
    }
    __syncthreads();
    {
        const int sl = t >> 4, c4 = t & 15;
        #pragma unroll
        for (int j = 0; j < 4; ++j) {
            const int s = sl + 16 * j;
            ushort4 v;
            v.x = lt[c4 * 4 + 0][s]; v.y = lt[c4 * 4 + 1][s];
            v.z = lt[c4 * 4 + 2][s]; v.w = lt[c4 * 4 + 3][s];
            *reinterpret_cast<ushort4*>(zt + (size_t)(b * 4096 + s0 + s) * DIM + c0 + c4 * 4) = v;
        }
    }
}

// m97-style screen GEMM: BM=128 pts, BN=256 codes, BK=64, single 48 KB buffer,
// 2-barrier K-loop, global_load_lds staging with XOR chunk swizzle, 8x4 wave tile.
// Emits per-(point, 16-code-group) min of s~ = e2[k] - 2*dot_bf16 -> tmin[n][128].
__global__ __launch_bounds__(256, 2) void screen_kernel(
    const ushort_t* __restrict__ zt, const ushort_t* __restrict__ eb,
    const float* __restrict__ e2, float* __restrict__ tmin)
{
    __shared__ char lds[49152];          // A: [0,16K) = 128 rows x 8 chunks; B: [16K,48K) = 256 x 8
    __shared__ float e2s[256];
    const int tid = threadIdx.x;
    const int bm = blockIdx.x & 255, bn = blockIdx.x >> 8;   // bm fast -> eb tile L2-hot
    const int n0 = bm * 128, k0 = bn * 256;
    e2s[tid] = e2[k0 + tid];
    const int wv = tid >> 6, lane = tid & 63;
    const int col = lane & 15, quad = lane >> 4;
    const int cswz = col & 7;

    f32x4 acc[8][4];
    #pragma unroll
    for (int i = 0; i < 8; ++i)
        #pragma unroll
        for (int j = 0; j < 4; ++j) acc[i][j] = (f32x4){0.f, 0.f, 0.f, 0.f};

    for (int kc = 0; kc < 4; ++kc) {
        __syncthreads();                 // prior-iter LDS reads done before overwrite
        #pragma unroll
        for (int it = 0; it < 12; ++it) {    // 3072 x 16B chunks: A 1024, B 2048
            const int L = tid + it * 256;
            if (L < 1024) {
                const int row = L >> 3, pc = L & 7, c = pc ^ (row & 7);
                async_copy16(lds + L * 16,
                             zt + ((size_t)(n0 + row) * DIM + kc * 64 + c * 8));
            } else {
                const int L2 = L - 1024;
                const int row = L2 >> 3, pc = L2 & 7, c = pc ^ (row & 7);
                async_copy16(lds + 16384 + L2 * 16,
                             eb + ((size_t)(k0 + row) * DIM + kc * 64 + c * 8));
            }
        }
        __syncthreads();                 // drains vmcnt: staged data visible
        #pragma unroll
        for (int s = 0; s < 2; ++s) {
            const int pc = (s * 4 + quad) ^ cswz;
            bf16x8 bq[4];
            #pragma unroll
            for (int j = 0; j < 4; ++j) {
                const int brow = wv * 64 + j * 16 + col;
                bq[j] = *reinterpret_cast<const bf16x8*>(lds + 16384 + (brow * 8 + pc) * 16);
            }
            #pragma unroll
            for (int i = 0; i < 8; ++i) {
                const int arow = i * 16 + col;
                const bf16x8 af = *reinterpret_cast<const bf16x8*>(lds + (arow * 8 + pc) * 16);
                #pragma unroll
                for (int j = 0; j < 4; ++j)
                    acc[i][j] = __builtin_amdgcn_mfma_f32_16x16x32_bf16(af, bq[j], acc[i][j], 0, 0, 0);
            }
        }
    }
    // epilogue: per-16-code-group minima (reduce across the 16 col lanes)
    #pragma unroll
    for (int i = 0; i < 8; ++i) {
        #pragma unroll
        for (int j = 0; j < 4; ++j) {
            const float e2v = e2s[wv * 64 + j * 16 + col];
            float tm[4];
            #pragma unroll
            for (int r = 0; r < 4; ++r) tm[r] = fmaf(-2.f, acc[i][j][r], e2v);
            #pragma unroll
            for (int off = 1; off < 16; off <<= 1)
                #pragma unroll
                for (int r = 0; r < 4; ++r) tm[r] = fminf(tm[r], __shfl_xor(tm[r], off));
            if (col == 0) {
                const int g = bn * 16 + wv * 4 + j;     // 16-code group index, 128 total
                const int nb = n0 + i * 16 + quad * 4;  // C/D row = quad*4+r
                #pragma unroll
                for (int r = 0; r < 4; ++r) tmin[(size_t)(nb + r) * 128 + g] = tm[r];
            }
        }
    }
}

// Fused exact re-resolve + z2 + gather + loss.
// R2: 32-point blocks (zs = 32x260x4 = 33,280 B) -> 4 blocks/CU, 16 waves/CU
// (2x the resident waves of the 64-pt version; the kernel is stall-bound at
// ~46 cy/instr so latency hiding capacity is the binding constraint).
// Same 4-point-parallel quad structure: each wave owns 8 points = 2 rounds.
// Per-point arithmetic (z2 chain, ascending-group candidate order, np-exact
// fmaf dot chain, lex-min tie-break) is IDENTICAL to the previous version.
__global__ __launch_bounds__(256, 4) void exact_kernel(
    const float* __restrict__ z, const float* __restrict__ emb,
    const float* __restrict__ e2, const float* __restrict__ tmin,
    float* __restrict__ outf, float* __restrict__ out_idx, float* __restrict__ partial)
{
    __shared__ float zs[32 * 260];       // [p][c] pitch 260 (33.3 KB): b128 row reads aligned
    const int tid = threadIdx.x;
    const int n0 = blockIdx.x * 32;
    const int b = n0 >> 12, s0 = n0 & 4095;
    {   // coalesced stage: float4 along s (8 lanes x 16B = 128B/channel), 32 ch/pass
        const int tq = tid & 7, cg = tid >> 3;
        for (int c = cg; c < DIM; c += 32) {
            const float4 u = *reinterpret_cast<const float4*>(
                z + (size_t)b * B_STRIDE + (size_t)c * S_STRIDE + s0 + tq * 4);
            zs[(tq * 4 + 0) * 260 + c] = u.x;
            zs[(tq * 4 + 1) * 260 + c] = u.y;
            zs[(tq * 4 + 2) * 260 + c] = u.z;
            zs[(tq * 4 + 3) * 260 + c] = u.w;
        }
    }
    __syncthreads();
    const int wv = tid >> 6, lane = tid & 63;
    const int quad = lane >> 4, ql = lane & 15;
    float lossacc = 0.f;

    // hoist all tmin loads: 8 group-minima per lane per round, statically indexed
    float a[2][8];
    #pragma unroll
    for (int t = 0; t < 2; ++t) {
        const int n = n0 + wv * 8 + t * 4 + quad;
        #pragma unroll
        for (int i = 0; i < 8; ++i) a[t][i] = tmin[(size_t)n * 128 + i * 16 + ql];
    }

    #pragma unroll
    for (int t = 0; t < 2; ++t) {
        const int p = wv * 8 + t * 4 + quad;     // this quad's point
        const int n = n0 + p;
        const float* zr = &zs[p * 260];
        // np-exact z2: the quad's 16 lanes run the 8-accumulator chains,
        // xor-tree combine in np order (identical chain to before, per quad)
        const int h = ql >> 3, j = ql & 7;
        float v0 = zr[h * 128 + j];
        float r = __fmul_rn(v0, v0);
        #pragma unroll
        for (int t2 = 1; t2 < 16; ++t2) {
            const float v = zr[h * 128 + j + 8 * t2];
            r = __fadd_rn(r, __fmul_rn(v, v));
        }
        { float v = __shfl_xor(r, 1); r = __fadd_rn(r, v); }
        { float v = __shfl_xor(r, 2); r = __fadd_rn(r, v); }
        { float v = __shfl_xor(r, 4); r = __fadd_rn(r, v); }
        const float z2n = __fadd_rn(__shfl(r, quad * 16), __shfl(r, quad * 16 + 8));
        // threshold over this point's 128 group minima (fminf: order-insensitive)
        float mn = fminf(fminf(fminf(a[t][0], a[t][1]), fminf(a[t][2], a[t][3])),
                         fminf(fminf(a[t][4], a[t][5]), fminf(a[t][6], a[t][7])));
        #pragma unroll
        for (int off = 1; off < 16; off <<= 1) mn = fminf(mn, __shfl_xor(mn, off));
        const float thr = mn + MARGIN;
        // per-quad 128-bit candidate mask, group g = i*16 + ql (ascending order kept)
        unsigned long long M0 = 0ull, M1 = 0ull;
        #pragma unroll
        for (int i = 0; i < 8; ++i) {
            const unsigned long long bal = __ballot(a[t][i] <= thr);
            const unsigned long long bits = (bal >> (quad * 16)) & 0xFFFFull;
            if (i < 4) M0 |= bits << (i * 16);
            else       M1 |= bits << ((i - 4) * 16);
        }
        float bs = FLT_MAX; int bk = 0x7FFFFFFF;
        while (__any((M0 | M1) != 0ull)) {
            int myt = -1;                          // quad-uniform next group, ascending
            if (M0) { myt = __ffsll(M0) - 1; M0 &= M0 - 1; }
            else if (M1) { myt = 64 + __ffsll(M1) - 1; M1 &= M1 - 1; }
            if (myt >= 0) {
                const int kg = myt * 16 + ql;
                const float* er = emb + (size_t)kg * DIM;
                float dot = 0.f;                   // np-exact ascending-c fmaf chain
                #pragma unroll 8
                for (int c4 = 0; c4 < 64; ++c4) {
                    const float4 ev = reinterpret_cast<const float4*>(er)[c4];
                    const float4 zv = *reinterpret_cast<const float4*>(zr + c4 * 4);  // quad-broadcast
                    dot = fmaf(zv.x, ev.x, dot);
                    dot = fmaf(zv.y, ev.y, dot);
                    dot = fmaf(zv.z, ev.z, dot);
                    dot = fmaf(zv.w, ev.w, dot);
                }
                const float A = __fadd_rn(z2n, e2[kg]);
                const float s = __fsub_rn(A, __fmul_rn(2.f, dot));
                if (s < bs || (s == bs && kg < bk)) { bs = s; bk = kg; }
            }
        }
        #pragma unroll
        for (int off = 1; off < 16; off <<= 1) {   // lex-min within quad = np.argmin
            const float os = __shfl_xor(bs, off);
            const int ok = __shfl_xor(bk, off);
            if (os < bs || (os == bs && ok < bk)) { bs = os; bk = ok; }
        }
        // gather z_q row (out[n][c] = emb[idx[n]][c]) + loss, float4 per quad-lane
        const float* eq = emb + (size_t)bk * DIM;
        float* op = outf + (size_t)n * DIM;
        #pragma unroll
        for (int jj = 0; jj < 4; ++jj) {
            const int c = (jj * 16 + ql) * 4;
            const float4 q4 = *reinterpret_cast<const float4*>(eq + c);
            *reinterpret_cast<float4*>(op + c) = q4;
            float d;
            d = q4.x - zr[c + 0]; lossacc = fmaf(d, d, lossacc);
            d = q4.y - zr[c + 1]; lossacc = fmaf(d, d, lossacc);
            d = q4.z - zr[c + 2]; lossacc = fmaf(d, d, lossacc);
            d = q4.w - zr[c + 3]; lossacc = fmaf(d, d, lossacc);
        }
        if (ql == 0) out_idx[n] = (float)bk;
    }
    #pragma unroll
    for (int off = 1; off < 64; off <<= 1) lossacc += __shfl_xor(lossacc, off);
    if (lane == 0) atomicAdd(&partial[blockIdx.x & 63], lossacc);
}

__global__ void finalize_kernel(const float* __restrict__ partial, float* __restrict__ out_loss) {
    float v = partial[threadIdx.x];          // 64 threads
    #pragma unroll
    for (int off = 1; off < 64; off <<= 1) v += __shfl_xor(v, off);
    if (threadIdx.x == 0)
        *out_loss = v * 1.25f / (float)N_ELEM;   // (1+BETA)*mean
}

extern "C" void kernel_launch(void* const* d_in, const int* in_sizes, int n_in,
                              void* d_out, int out_size, void* d_ws, size_t ws_size,
                              hipStream_t stream) {
    const float* z = (const float*)d_in[0];
    const float* emb = (const float*)d_in[1];
    char* ws = (char*)d_ws;
    float* partial = (float*)(ws + WS_PARTIAL);
    float* e2 = (float*)(ws + WS_E2);
    ushort_t* eb = (ushort_t*)(ws + WS_EB);
    ushort_t* zt = (ushort_t*)(ws + WS_ZT);
    float* tmin = (float*)(ws + WS_TMIN);
    float* outf = (float*)d_out;
    float* out_loss = outf + N_ELEM;
    float* out_idx = outf + N_ELEM + 1;

    conv_emb_kernel<<<512, 256, 0, stream>>>(emb, eb);
    e2p_kernel<<<N_CODES / 256, 256, 0, stream>>>(emb, e2, partial);
    transpose_kernel<<<2048, 256, 0, stream>>>(z, zt);
    screen_kernel<<<2048, 256, 0, stream>>>(zt, eb, e2, tmin);
    exact_kernel<<<N_PTS / 32, 256, 0, stream>>>(z, emb, e2, tmin, outf, out_idx, partial);
    finalize_kernel<<<1, 64, 0, stream>>>(partial, out_loss);
}

// Round 3
// 282.615 us; speedup vs baseline: 1.0215x; 1.0215x over previous
//
#include <hip/hip_runtime.h>
#include <float.h>

// Problem constants
#define N_PTS    32768       // 8*16*16*16 spatial positions
#define N_CODES  2048
#define DIM      256
#define S_STRIDE 4096        // d*h*w stride of channel dim in z (floats)
#define B_STRIDE 1048576     // per-batch stride in z (256*4096 floats)
#define N_ELEM   8388608     // total z elements

#define MARGIN   8e-4f       // >= 2x |screen-score - np-score| bound (validated R5-R7)

// ws layout (bytes), 512-aligned
#define WS_PARTIAL 0          // float[64]
#define WS_E2      512        // float[2048]             -> 8704
#define WS_EB      8704       // bf16[2048*256] 1 MB     -> 1057280
#define WS_ZT      1057280    // bf16[32768*256] 16.8 MB -> 17834496
#define WS_TMIN    17834496   // float[32768*128] 16.8MB -> 34611712
// embp (2 MB, float4-permuted emb for the exact dot) OVERLAYS WS_ZT: zt is
// dead after screen_kernel; perm_emb_kernel runs between screen and exact.
#define WS_EMBP    WS_ZT

typedef unsigned short ushort_t;
typedef short bf16x8 __attribute__((ext_vector_type(8)));
typedef float f32x4 __attribute__((ext_vector_type(4)));

__device__ __forceinline__ ushort_t f2bf(float v) {   // RNE fp32->bf16 (no NaN in data)
    const unsigned u = __float_as_uint(v);
    return (ushort_t)((u + 0x7FFFu + ((u >> 16) & 1u)) >> 16);
}

__device__ __forceinline__ void async_copy16(void* lds, const void* g) {
    __builtin_amdgcn_global_load_lds(
        (const __attribute__((address_space(1))) unsigned int*)g,
        (__attribute__((address_space(3))) unsigned int*)lds, 16, 0, 0);
}

__device__ __forceinline__ f32x4 nt_load4(const float* p) {
    return __builtin_nontemporal_load(reinterpret_cast<const f32x4*>(p));
}
__device__ __forceinline__ void nt_store4(float* p, f32x4 v) {
    __builtin_nontemporal_store(v, reinterpret_cast<f32x4*>(p));
}

// emb fp32 [k][256] -> bf16 eb [k][256] (coalesced)
__global__ void conv_emb_kernel(const float* __restrict__ emb, ushort_t* __restrict__ eb) {
    const int gid = blockIdx.x * 256 + threadIdx.x;   // 512 blocks: 2048 codes x 64 float4
    const int k = gid >> 6, c4 = gid & 63;
    const float4 u = *reinterpret_cast<const float4*>(emb + (size_t)k * DIM + c4 * 4);
    ushort4 v; v.x = f2bf(u.x); v.y = f2bf(u.y); v.z = f2bf(u.z); v.w = f2bf(u.w);
    *reinterpret_cast<ushort4*>(eb + (size_t)k * DIM + c4 * 4) = v;
}

// emb fp32 [2048][256] -> embp float4[(g*64+c4)*16+ql] = emb[g*16+ql][c4*4..+3].
// Pure permutation (bit-identical values); makes the exact-dot's 16-lane quad
// read 256 B CONTIGUOUS per instruction instead of 16 lines at 1 KB stride.
__global__ void perm_emb_kernel(const float* __restrict__ emb, float* __restrict__ embp) {
    const int gid = blockIdx.x * 256 + threadIdx.x;   // 512 blocks: 131072 float4s
    const int ql = gid & 15, c4 = (gid >> 4) & 63, g = gid >> 10;
    const float4 u = reinterpret_cast<const float4*>(emb)[(size_t)(g * 16 + ql) * 64 + c4];
    reinterpret_cast<float4*>(embp)[gid] = u;         // gid == (g*64+c4)*16+ql
}

// e2[k] = np-pairwise sum of emb[k][:]^2; also zeroes loss partials.
__global__ void e2p_kernel(const float* __restrict__ emb, float* __restrict__ e2,
                           float* __restrict__ partial) {
    const int k = blockIdx.x * 256 + threadIdx.x;
    if (blockIdx.x == 0 && threadIdx.x < 64) partial[threadIdx.x] = 0.f;
    const float* base = emb + (size_t)k * DIM;
    float half[2];
    #pragma unroll
    for (int h = 0; h < 2; ++h) {
        float r[8];
        #pragma unroll
        for (int j = 0; j < 8; ++j) { const float v = base[h * 128 + j]; r[j] = __fmul_rn(v, v); }
        for (int t = 8; t < 128; t += 8)
            #pragma unroll
            for (int j = 0; j < 8; ++j) {
                const float v = base[h * 128 + t + j];
                r[j] = __fadd_rn(r[j], __fmul_rn(v, v));
            }
        half[h] = __fadd_rn(__fadd_rn(__fadd_rn(r[0], r[1]), __fadd_rn(r[2], r[3])),
                            __fadd_rn(__fadd_rn(r[4], r[5]), __fadd_rn(r[6], r[7])));
    }
    e2[k] = __fadd_rn(half[0], half[1]);
}

// z [8][256][4096] fp32 -> z_t [n][c] bf16 (pitch 256), 64x64 LDS transpose tiles.
__global__ void transpose_kernel(const float* __restrict__ z, ushort_t* __restrict__ zt) {
    __shared__ ushort_t lt[64][72];
    const int bx = blockIdx.x;            // 2048 = 8 b x 4 cg x 64 sg
    const int b = bx >> 8, cg = (bx >> 6) & 3, sg = bx & 63;
    const int c0 = cg * 64, s0 = sg * 64;
    const int t = threadIdx.x;
    {
        const int cl = t >> 4, s4 = t & 15;
        #pragma unroll
        for (int j = 0; j < 4; ++j) {
            const int c = cl + 16 * j;
            const float4 u = *reinterpret_cast<const float4*>(
                z + (size_t)b * B_STRIDE + (size_t)(c0 + c) * S_STRIDE + s0 + s4 * 4);
            ushort4 v; v.x = f2bf(u.x); v.y = f2bf(u.y); v.z = f2bf(u.z); v.w = f2bf(u.w);
            *reinterpret_cast<ushort4*>(&lt[c][s4 * 4]) = v;
        }
    }
    __syncthreads();
    {
        const int sl = t >> 4, c4 = t & 15;
        #pragma unroll
        for (int j = 0; j < 4; ++j) {
            const int s = sl + 16 * j;
            ushort4 v;
            v.x = lt[c4 * 4 + 0][s]; v.y = lt[c4 * 4 + 1][s];
            v.z = lt[c4 * 4 + 2][s]; v.w = lt[c4 * 4 + 3][s];
            *reinterpret_cast<ushort4*>(zt + (size_t)(b * 4096 + s0 + s) * DIM + c0 + c4 * 4) = v;
        }
    }
}

// m97-style screen GEMM: BM=128 pts, BN=256 codes, BK=64, single 48 KB buffer,
// 2-barrier K-loop, global_load_lds staging with XOR chunk swizzle, 8x4 wave tile.
// Emits per-(point, 16-code-group) min of s~ = e2[k] - 2*dot_bf16 -> tmin[n][128].
__global__ __launch_bounds__(256, 2) void screen_kernel(
    const ushort_t* __restrict__ zt, const ushort_t* __restrict__ eb,
    const float* __restrict__ e2, float* __restrict__ tmin)
{
    __shared__ char lds[49152];          // A: [0,16K) = 128 rows x 8 chunks; B: [16K,48K) = 256 x 8
    __shared__ float e2s[256];
    const int tid = threadIdx.x;
    const int bm = blockIdx.x & 255, bn = blockIdx.x >> 8;   // bm fast -> eb tile L2-hot
    const int n0 = bm * 128, k0 = bn * 256;
    e2s[tid] = e2[k0 + tid];
    const int wv = tid >> 6, lane = tid & 63;
    const int col = lane & 15, quad = lane >> 4;
    const int cswz = col & 7;

    f32x4 acc[8][4];
    #pragma unroll
    for (int i = 0; i < 8; ++i)
        #pragma unroll
        for (int j = 0; j < 4; ++j) acc[i][j] = (f32x4){0.f, 0.f, 0.f, 0.f};

    for (int kc = 0; kc < 4; ++kc) {
        __syncthreads();                 // prior-iter LDS reads done before overwrite
        #pragma unroll
        for (int it = 0; it < 12; ++it) {    // 3072 x 16B chunks: A 1024, B 2048
            const int L = tid + it * 256;
            if (L < 1024) {
                const int row = L >> 3, pc = L & 7, c = pc ^ (row & 7);
                async_copy16(lds + L * 16,
                             zt + ((size_t)(n0 + row) * DIM + kc * 64 + c * 8));
            } else {
                const int L2 = L - 1024;
                const int row = L2 >> 3, pc = L2 & 7, c = pc ^ (row & 7);
                async_copy16(lds + 16384 + L2 * 16,
                             eb + ((size_t)(k0 + row) * DIM + kc * 64 + c * 8));
            }
        }
        __syncthreads();                 // drains vmcnt: staged data visible
        #pragma unroll
        for (int s = 0; s < 2; ++s) {
            const int pc = (s * 4 + quad) ^ cswz;
            bf16x8 bq[4];
            #pragma unroll
            for (int j = 0; j < 4; ++j) {
                const int brow = wv * 64 + j * 16 + col;
                bq[j] = *reinterpret_cast<const bf16x8*>(lds + 16384 + (brow * 8 + pc) * 16);
            }
            #pragma unroll
            for (int i = 0; i < 8; ++i) {
                const int arow = i * 16 + col;
                const bf16x8 af = *reinterpret_cast<const bf16x8*>(lds + (arow * 8 + pc) * 16);
                #pragma unroll
                for (int j = 0; j < 4; ++j)
                    acc[i][j] = __builtin_amdgcn_mfma_f32_16x16x32_bf16(af, bq[j], acc[i][j], 0, 0, 0);
            }
        }
    }
    // epilogue: per-16-code-group minima (reduce across the 16 col lanes)
    #pragma unroll
    for (int i = 0; i < 8; ++i) {
        #pragma unroll
        for (int j = 0; j < 4; ++j) {
            const float e2v = e2s[wv * 64 + j * 16 + col];
            float tm[4];
            #pragma unroll
            for (int r = 0; r < 4; ++r) tm[r] = fmaf(-2.f, acc[i][j][r], e2v);
            #pragma unroll
            for (int off = 1; off < 16; off <<= 1)
                #pragma unroll
                for (int r = 0; r < 4; ++r) tm[r] = fminf(tm[r], __shfl_xor(tm[r], off));
            if (col == 0) {
                const int g = bn * 16 + wv * 4 + j;     // 16-code group index, 128 total
                const int nb = n0 + i * 16 + quad * 4;  // C/D row = quad*4+r
                #pragma unroll
                for (int r = 0; r < 4; ++r) tmin[(size_t)(nb + r) * 128 + g] = tm[r];
            }
        }
    }
}

// Fused exact re-resolve + z2 + gather + loss.
// R3: the candidate-dot reads the PERMUTED embp layout: quad's 16 lanes read
// 256 B contiguous per instruction (was: 16 lines at 1 KB stride -> L2-request
// saturation, invariant to occupancy per R2's A/B). Values + chain order are
// bit-identical to before. nt hints keep the 66 MB z/tmin/outf stream from
// evicting embp in L2. launch_bounds(256,3): VGPR headroom for 16 in-flight
// float4 loads in the dot loop, 3 blocks/CU.
__global__ __launch_bounds__(256, 3) void exact_kernel(
    const float* __restrict__ z, const float* __restrict__ emb,
    const float* __restrict__ embp,
    const float* __restrict__ e2, const float* __restrict__ tmin,
    float* __restrict__ outf, float* __restrict__ out_idx, float* __restrict__ partial)
{
    __shared__ float zs[32 * 260];       // [p][c] pitch 260 (33.3 KB)
    const int tid = threadIdx.x;
    const int n0 = blockIdx.x * 32;
    const int b = n0 >> 12, s0 = n0 & 4095;
    {   // coalesced stage: float4 along s (8 lanes x 16B = 128B/channel), 32 ch/pass
        const int tq = tid & 7, cg = tid >> 3;
        for (int c = cg; c < DIM; c += 32) {
            const f32x4 u = nt_load4(
                z + (size_t)b * B_STRIDE + (size_t)c * S_STRIDE + s0 + tq * 4);
            zs[(tq * 4 + 0) * 260 + c] = u[0];
            zs[(tq * 4 + 1) * 260 + c] = u[1];
            zs[(tq * 4 + 2) * 260 + c] = u[2];
            zs[(tq * 4 + 3) * 260 + c] = u[3];
        }
    }
    __syncthreads();
    const int wv = tid >> 6, lane = tid & 63;
    const int quad = lane >> 4, ql = lane & 15;
    float lossacc = 0.f;

    // hoist all tmin loads: 8 group-minima per lane per round, statically indexed
    float a[2][8];
    #pragma unroll
    for (int t = 0; t < 2; ++t) {
        const int n = n0 + wv * 8 + t * 4 + quad;
        #pragma unroll
        for (int i = 0; i < 8; ++i)
            a[t][i] = __builtin_nontemporal_load(tmin + (size_t)n * 128 + i * 16 + ql);
    }

    #pragma unroll
    for (int t = 0; t < 2; ++t) {
        const int p = wv * 8 + t * 4 + quad;     // this quad's point
        const int n = n0 + p;
        const float* zr = &zs[p * 260];
        // np-exact z2: the quad's 16 lanes run the 8-accumulator chains,
        // xor-tree combine in np order (identical chain to before, per quad)
        const int h = ql >> 3, j = ql & 7;
        float v0 = zr[h * 128 + j];
        float r = __fmul_rn(v0, v0);
        #pragma unroll
        for (int t2 = 1; t2 < 16; ++t2) {
            const float v = zr[h * 128 + j + 8 * t2];
            r = __fadd_rn(r, __fmul_rn(v, v));
        }
        { float v = __shfl_xor(r, 1); r = __fadd_rn(r, v); }
        { float v = __shfl_xor(r, 2); r = __fadd_rn(r, v); }
        { float v = __shfl_xor(r, 4); r = __fadd_rn(r, v); }
        const float z2n = __fadd_rn(__shfl(r, quad * 16), __shfl(r, quad * 16 + 8));
        // threshold over this point's 128 group minima (fminf: order-insensitive)
        float mn = fminf(fminf(fminf(a[t][0], a[t][1]), fminf(a[t][2], a[t][3])),
                         fminf(fminf(a[t][4], a[t][5]), fminf(a[t][6], a[t][7])));
        #pragma unroll
        for (int off = 1; off < 16; off <<= 1) mn = fminf(mn, __shfl_xor(mn, off));
        const float thr = mn + MARGIN;
        // per-quad 128-bit candidate mask, group g = i*16 + ql (ascending order kept)
        unsigned long long M0 = 0ull, M1 = 0ull;
        #pragma unroll
        for (int i = 0; i < 8; ++i) {
            const unsigned long long bal = __ballot(a[t][i] <= thr);
            const unsigned long long bits = (bal >> (quad * 16)) & 0xFFFFull;
            if (i < 4) M0 |= bits << (i * 16);
            else       M1 |= bits << ((i - 4) * 16);
        }
        float bs = FLT_MAX; int bk = 0x7FFFFFFF;
        while (__any((M0 | M1) != 0ull)) {
            int myt = -1;                          // quad-uniform next group, ascending
            if (M0) { myt = __ffsll(M0) - 1; M0 &= M0 - 1; }
            else if (M1) { myt = 64 + __ffsll(M1) - 1; M1 &= M1 - 1; }
            if (myt >= 0) {
                const int kg = myt * 16 + ql;
                // permuted layout: quad reads 256 B contiguous per c4 step
                const float4* gp = reinterpret_cast<const float4*>(embp)
                                   + (size_t)myt * 1024 + ql;
                float dot = 0.f;                   // np-exact ascending-c fmaf chain
                #pragma unroll 16
                for (int c4 = 0; c4 < 64; ++c4) {
                    const float4 ev = gp[c4 * 16];
                    const float4 zv = *reinterpret_cast<const float4*>(zr + c4 * 4);  // quad-broadcast
                    dot = fmaf(zv.x, ev.x, dot);
                    dot = fmaf(zv.y, ev.y, dot);
                    dot = fmaf(zv.z, ev.z, dot);
                    dot = fmaf(zv.w, ev.w, dot);
                }
                const float A = __fadd_rn(z2n, e2[kg]);
                const float s = __fsub_rn(A, __fmul_rn(2.f, dot));
                if (s < bs || (s == bs && kg < bk)) { bs = s; bk = kg; }
            }
        }
        #pragma unroll
        for (int off = 1; off < 16; off <<= 1) {   // lex-min within quad = np.argmin
            const float os = __shfl_xor(bs, off);
            const int ok = __shfl_xor(bk, off);
            if (os < bs || (os == bs && ok < bk)) { bs = os; bk = ok; }
        }
        // gather z_q row (out[n][c] = emb[idx[n]][c]) + loss, float4 per quad-lane
        const float* eq = emb + (size_t)bk * DIM;
        float* op = outf + (size_t)n * DIM;
        #pragma unroll
        for (int jj = 0; jj < 4; ++jj) {
            const int c = (jj * 16 + ql) * 4;
            const float4 q4 = *reinterpret_cast<const float4*>(eq + c);
            f32x4 q; q[0] = q4.x; q[1] = q4.y; q[2] = q4.z; q[3] = q4.w;
            nt_store4(op + c, q);
            float d;
            d = q4.x - zr[c + 0]; lossacc = fmaf(d, d, lossacc);
            d = q4.y - zr[c + 1]; lossacc = fmaf(d, d, lossacc);
            d = q4.z - zr[c + 2]; lossacc = fmaf(d, d, lossacc);
            d = q4.w - zr[c + 3]; lossacc = fmaf(d, d, lossacc);
        }
        if (ql == 0) out_idx[n] = (float)bk;
    }
    #pragma unroll
    for (int off = 1; off < 64; off <<= 1) lossacc += __shfl_xor(lossacc, off);
    if (lane == 0) atomicAdd(&partial[blockIdx.x & 63], lossacc);
}

__global__ void finalize_kernel(const float* __restrict__ partial, float* __restrict__ out_loss) {
    float v = partial[threadIdx.x];          // 64 threads
    #pragma unroll
    for (int off = 1; off < 64; off <<= 1) v += __shfl_xor(v, off);
    if (threadIdx.x == 0)
        *out_loss = v * 1.25f / (float)N_ELEM;   // (1+BETA)*mean
}

extern "C" void kernel_launch(void* const* d_in, const int* in_sizes, int n_in,
                              void* d_out, int out_size, void* d_ws, size_t ws_size,
                              hipStream_t stream) {
    const float* z = (const float*)d_in[0];
    const float* emb = (const float*)d_in[1];
    char* ws = (char*)d_ws;
    float* partial = (float*)(ws + WS_PARTIAL);
    float* e2 = (float*)(ws + WS_E2);
    ushort_t* eb = (ushort_t*)(ws + WS_EB);
    ushort_t* zt = (ushort_t*)(ws + WS_ZT);
    float* embp = (float*)(ws + WS_EMBP);    // overlays zt (dead after screen)
    float* tmin = (float*)(ws + WS_TMIN);
    float* outf = (float*)d_out;
    float* out_loss = outf + N_ELEM;
    float* out_idx = outf + N_ELEM + 1;

    conv_emb_kernel<<<512, 256, 0, stream>>>(emb, eb);
    e2p_kernel<<<N_CODES / 256, 256, 0, stream>>>(emb, e2, partial);
    transpose_kernel<<<2048, 256, 0, stream>>>(z, zt);
    screen_kernel<<<2048, 256, 0, stream>>>(zt, eb, e2, tmin);
    perm_emb_kernel<<<512, 256, 0, stream>>>(emb, embp);   // after screen: reuses zt region
    exact_kernel<<<N_PTS / 32, 256, 0, stream>>>(z, emb, embp, e2, tmin, outf, out_idx, partial);
    finalize_kernel<<<1, 64, 0, stream>>>(partial, out_loss);
}

// Round 4
// 236.232 us; speedup vs baseline: 1.2221x; 1.1963x over previous
//
#include <hip/hip_runtime.h>
#include <float.h>

// Problem constants
#define N_PTS    32768       // 8*16*16*16 spatial positions
#define N_CODES  2048
#define DIM      256
#define S_STRIDE 4096        // d*h*w stride of channel dim in z (floats)
#define B_STRIDE 1048576     // per-batch stride in z (256*4096 floats)
#define N_ELEM   8388608     // total z elements

#define MARGIN   8e-4f       // >= 2x |screen-score - np-score| bound (validated R5-R7)

// ws layout (bytes), 512-aligned
#define WS_PARTIAL 0          // float[64]
#define WS_E2      512        // float[2048]             -> 8704
#define WS_EB      8704       // bf16[2048*256] 1 MB     -> 1057280
#define WS_ZT      1057280    // bf16[32768*256] 16.8 MB -> 17834496
#define WS_TMIN    17834496   // float[32768*128] 16.8MB -> 34611712
// embp (2 MB, float4-permuted emb for the exact dot) OVERLAYS WS_ZT: zt is
// dead after screen_kernel; perm_emb_kernel runs between screen and exact.
#define WS_EMBP    WS_ZT

typedef unsigned short ushort_t;
typedef short bf16x8 __attribute__((ext_vector_type(8)));
typedef float f32x4 __attribute__((ext_vector_type(4)));

__device__ __forceinline__ ushort_t f2bf(float v) {   // RNE fp32->bf16 (no NaN in data)
    const unsigned u = __float_as_uint(v);
    return (ushort_t)((u + 0x7FFFu + ((u >> 16) & 1u)) >> 16);
}

__device__ __forceinline__ void async_copy16(void* lds, const void* g) {
    __builtin_amdgcn_global_load_lds(
        (const __attribute__((address_space(1))) unsigned int*)g,
        (__attribute__((address_space(3))) unsigned int*)lds, 16, 0, 0);
}

__device__ __forceinline__ void nt_store4(float* p, f32x4 v) {
    __builtin_nontemporal_store(v, reinterpret_cast<f32x4*>(p));
}

// emb fp32 [k][256] -> bf16 eb [k][256] (coalesced)
__global__ void conv_emb_kernel(const float* __restrict__ emb, ushort_t* __restrict__ eb) {
    const int gid = blockIdx.x * 256 + threadIdx.x;   // 512 blocks: 2048 codes x 64 float4
    const int k = gid >> 6, c4 = gid & 63;
    const float4 u = *reinterpret_cast<const float4*>(emb + (size_t)k * DIM + c4 * 4);
    ushort4 v; v.x = f2bf(u.x); v.y = f2bf(u.y); v.z = f2bf(u.z); v.w = f2bf(u.w);
    *reinterpret_cast<ushort4*>(eb + (size_t)k * DIM + c4 * 4) = v;
}

// emb fp32 [2048][256] -> embp float4[(g*64+c4)*16+ql] = emb[g*16+ql][c4*4..+3].
// Pure permutation (bit-identical values); makes the exact-dot's 16-lane quad
// read 256 B CONTIGUOUS per instruction instead of 16 lines at 1 KB stride.
__global__ void perm_emb_kernel(const float* __restrict__ emb, float* __restrict__ embp) {
    const int gid = blockIdx.x * 256 + threadIdx.x;   // 512 blocks: 131072 float4s
    const int ql = gid & 15, c4 = (gid >> 4) & 63, g = gid >> 10;
    const float4 u = reinterpret_cast<const float4*>(emb)[(size_t)(g * 16 + ql) * 64 + c4];
    reinterpret_cast<float4*>(embp)[gid] = u;         // gid == (g*64+c4)*16+ql
}

// e2[k] = np-pairwise sum of emb[k][:]^2; also zeroes loss partials.
__global__ void e2p_kernel(const float* __restrict__ emb, float* __restrict__ e2,
                           float* __restrict__ partial) {
    const int k = blockIdx.x * 256 + threadIdx.x;
    if (blockIdx.x == 0 && threadIdx.x < 64) partial[threadIdx.x] = 0.f;
    const float* base = emb + (size_t)k * DIM;
    float half[2];
    #pragma unroll
    for (int h = 0; h < 2; ++h) {
        float r[8];
        #pragma unroll
        for (int j = 0; j < 8; ++j) { const float v = base[h * 128 + j]; r[j] = __fmul_rn(v, v); }
        for (int t = 8; t < 128; t += 8)
            #pragma unroll
            for (int j = 0; j < 8; ++j) {
                const float v = base[h * 128 + t + j];
                r[j] = __fadd_rn(r[j], __fmul_rn(v, v));
            }
        half[h] = __fadd_rn(__fadd_rn(__fadd_rn(r[0], r[1]), __fadd_rn(r[2], r[3])),
                            __fadd_rn(__fadd_rn(r[4], r[5]), __fadd_rn(r[6], r[7])));
    }
    e2[k] = __fadd_rn(half[0], half[1]);
}

// z [8][256][4096] fp32 -> z_t [n][c] bf16 (pitch 256), 64x64 LDS transpose tiles.
__global__ void transpose_kernel(const float* __restrict__ z, ushort_t* __restrict__ zt) {
    __shared__ ushort_t lt[64][72];
    const int bx = blockIdx.x;            // 2048 = 8 b x 4 cg x 64 sg
    const int b = bx >> 8, cg = (bx >> 6) & 3, sg = bx & 63;
    const int c0 = cg * 64, s0 = sg * 64;
    const int t = threadIdx.x;
    {
        const int cl = t >> 4, s4 = t & 15;
        #pragma unroll
        for (int j = 0; j < 4; ++j) {
            const int c = cl + 16 * j;
            const float4 u = *reinterpret_cast<const float4*>(
                z + (size_t)b * B_STRIDE + (size_t)(c0 + c) * S_STRIDE + s0 + s4 * 4);
            ushort4 v; v.x = f2bf(u.x); v.y = f2bf(u.y); v.z = f2bf(u.z); v.w = f2bf(u.w);
            *reinterpret_cast<ushort4*>(&lt[c][s4 * 4]) = v;
        }
    }
    __syncthreads();
    {
        const int sl = t >> 4, c4 = t & 15;
        #pragma unroll
        for (int j = 0; j < 4; ++j) {
            const int s = sl + 16 * j;
            ushort4 v;
            v.x = lt[c4 * 4 + 0][s]; v.y = lt[c4 * 4 + 1][s];
            v.z = lt[c4 * 4 + 2][s]; v.w = lt[c4 * 4 + 3][s];
            *reinterpret_cast<ushort4*>(zt + (size_t)(b * 4096 + s0 + s) * DIM + c0 + c4 * 4) = v;
        }
    }
}

// m97-style screen GEMM: BM=128 pts, BN=256 codes, BK=64, single 48 KB buffer,
// 2-barrier K-loop, global_load_lds staging with XOR chunk swizzle, 8x4 wave tile.
// R4: XCD-chunked block order. XCD c (= blockIdx%8 round-robin) owns bm in
// [c*32, c*32+32): its 2 MB zt slice fits the per-XCD 4 MB L2 and is reused
// across all 8 bn passes (was bm-fast: each bn pass re-fetched all 16.8 MB zt
// from HBM; eb at 1 MB is L2-resident under any order).
// Emits per-(point, 16-code-group) min of s~ = e2[k] - 2*dot_bf16 -> tmin[n][128].
__global__ __launch_bounds__(256, 2) void screen_kernel(
    const ushort_t* __restrict__ zt, const ushort_t* __restrict__ eb,
    const float* __restrict__ e2, float* __restrict__ tmin)
{
    __shared__ char lds[49152];          // A: [0,16K) = 128 rows x 8 chunks; B: [16K,48K) = 256 x 8
    __shared__ float e2s[256];
    const int tid = threadIdx.x;
    const int x = blockIdx.x;            // 2048 = 8 xcd-chunk x 32 bm-off x 8 bn
    const int bm = (x & 7) * 32 + ((x >> 3) & 31), bn = x >> 8;
    const int n0 = bm * 128, k0 = bn * 256;
    e2s[tid] = e2[k0 + tid];
    const int wv = tid >> 6, lane = tid & 63;
    const int col = lane & 15, quad = lane >> 4;
    const int cswz = col & 7;

    f32x4 acc[8][4];
    #pragma unroll
    for (int i = 0; i < 8; ++i)
        #pragma unroll
        for (int j = 0; j < 4; ++j) acc[i][j] = (f32x4){0.f, 0.f, 0.f, 0.f};

    for (int kc = 0; kc < 4; ++kc) {
        __syncthreads();                 // prior-iter LDS reads done before overwrite
        #pragma unroll
        for (int it = 0; it < 12; ++it) {    // 3072 x 16B chunks: A 1024, B 2048
            const int L = tid + it * 256;
            if (L < 1024) {
                const int row = L >> 3, pc = L & 7, c = pc ^ (row & 7);
                async_copy16(lds + L * 16,
                             zt + ((size_t)(n0 + row) * DIM + kc * 64 + c * 8));
            } else {
                const int L2 = L - 1024;
                const int row = L2 >> 3, pc = L2 & 7, c = pc ^ (row & 7);
                async_copy16(lds + 16384 + L2 * 16,
                             eb + ((size_t)(k0 + row) * DIM + kc * 64 + c * 8));
            }
        }
        __syncthreads();                 // drains vmcnt: staged data visible
        #pragma unroll
        for (int s = 0; s < 2; ++s) {
            const int pc = (s * 4 + quad) ^ cswz;
            bf16x8 bq[4];
            #pragma unroll
            for (int j = 0; j < 4; ++j) {
                const int brow = wv * 64 + j * 16 + col;
                bq[j] = *reinterpret_cast<const bf16x8*>(lds + 16384 + (brow * 8 + pc) * 16);
            }
            #pragma unroll
            for (int i = 0; i < 8; ++i) {
                const int arow = i * 16 + col;
                const bf16x8 af = *reinterpret_cast<const bf16x8*>(lds + (arow * 8 + pc) * 16);
                #pragma unroll
                for (int j = 0; j < 4; ++j)
                    acc[i][j] = __builtin_amdgcn_mfma_f32_16x16x32_bf16(af, bq[j], acc[i][j], 0, 0, 0);
            }
        }
    }
    // epilogue: per-16-code-group minima (reduce across the 16 col lanes)
    #pragma unroll
    for (int i = 0; i < 8; ++i) {
        #pragma unroll
        for (int j = 0; j < 4; ++j) {
            const float e2v = e2s[wv * 64 + j * 16 + col];
            float tm[4];
            #pragma unroll
            for (int r = 0; r < 4; ++r) tm[r] = fmaf(-2.f, acc[i][j][r], e2v);
            #pragma unroll
            for (int off = 1; off < 16; off <<= 1)
                #pragma unroll
                for (int r = 0; r < 4; ++r) tm[r] = fminf(tm[r], __shfl_xor(tm[r], off));
            if (col == 0) {
                const int g = bn * 16 + wv * 4 + j;     // 16-code group index, 128 total
                const int nb = n0 + i * 16 + quad * 4;  // C/D row = quad*4+r
                #pragma unroll
                for (int r = 0; r < 4; ++r) tmin[(size_t)(nb + r) * 128 + g] = tm[r];
            }
        }
    }
}

// Fused exact re-resolve + z2 + gather + loss.
// R4: explicit MLP in the candidate dot. R3's compiler schedule used 52 VGPRs
// -> loads issued in ~4-deep batches, each drained at full L2/LDS latency
// (~5-7k cy per candidate group; the real reason R2's occupancy doubling and
// R3's coalescing were neutral). Now: 8 segments of 8 c4-steps; pre[8] holds
// segment s+1's embp loads in flight while segment s's fmaf chain retires.
// Chain order (ascending c4; x,y,z,w) is bit-identical to np-exact validated.
__global__ __launch_bounds__(256, 3) void exact_kernel(
    const float* __restrict__ z, const float* __restrict__ emb,
    const float* __restrict__ embp,
    const float* __restrict__ e2, const float* __restrict__ tmin,
    float* __restrict__ outf, float* __restrict__ out_idx, float* __restrict__ partial)
{
    __shared__ float zs[32 * 260];       // [p][c] pitch 260 (33.3 KB)
    const int tid = threadIdx.x;
    const int n0 = blockIdx.x * 32;
    const int b = n0 >> 12, s0 = n0 & 4095;
    {   // coalesced stage: float4 along s (8 lanes x 16B = 128B/channel), 32 ch/pass
        const int tq = tid & 7, cg = tid >> 3;
        for (int c = cg; c < DIM; c += 32) {
            const float4 u = *reinterpret_cast<const float4*>(
                z + (size_t)b * B_STRIDE + (size_t)c * S_STRIDE + s0 + tq * 4);
            zs[(tq * 4 + 0) * 260 + c] = u.x;
            zs[(tq * 4 + 1) * 260 + c] = u.y;
            zs[(tq * 4 + 2) * 260 + c] = u.z;
            zs[(tq * 4 + 3) * 260 + c] = u.w;
        }
    }
    __syncthreads();
    const int wv = tid >> 6, lane = tid & 63;
    const int quad = lane >> 4, ql = lane & 15;
    float lossacc = 0.f;

    // hoist all tmin loads: 8 group-minima per lane per round, statically indexed
    float a[2][8];
    #pragma unroll
    for (int t = 0; t < 2; ++t) {
        const int n = n0 + wv * 8 + t * 4 + quad;
        #pragma unroll
        for (int i = 0; i < 8; ++i)
            a[t][i] = __builtin_nontemporal_load(tmin + (size_t)n * 128 + i * 16 + ql);
    }

    #pragma unroll
    for (int t = 0; t < 2; ++t) {
        const int p = wv * 8 + t * 4 + quad;     // this quad's point
        const int n = n0 + p;
        const float* zr = &zs[p * 260];
        // np-exact z2: the quad's 16 lanes run the 8-accumulator chains,
        // xor-tree combine in np order (identical chain to before, per quad)
        const int h = ql >> 3, j = ql & 7;
        float v0 = zr[h * 128 + j];
        float r = __fmul_rn(v0, v0);
        #pragma unroll
        for (int t2 = 1; t2 < 16; ++t2) {
            const float v = zr[h * 128 + j + 8 * t2];
            r = __fadd_rn(r, __fmul_rn(v, v));
        }
        { float v = __shfl_xor(r, 1); r = __fadd_rn(r, v); }
        { float v = __shfl_xor(r, 2); r = __fadd_rn(r, v); }
        { float v = __shfl_xor(r, 4); r = __fadd_rn(r, v); }
        const float z2n = __fadd_rn(__shfl(r, quad * 16), __shfl(r, quad * 16 + 8));
        // threshold over this point's 128 group minima (fminf: order-insensitive)
        float mn = fminf(fminf(fminf(a[t][0], a[t][1]), fminf(a[t][2], a[t][3])),
                         fminf(fminf(a[t][4], a[t][5]), fminf(a[t][6], a[t][7])));
        #pragma unroll
        for (int off = 1; off < 16; off <<= 1) mn = fminf(mn, __shfl_xor(mn, off));
        const float thr = mn + MARGIN;
        // per-quad 128-bit candidate mask, group g = i*16 + ql (ascending order kept)
        unsigned long long M0 = 0ull, M1 = 0ull;
        #pragma unroll
        for (int i = 0; i < 8; ++i) {
            const unsigned long long bal = __ballot(a[t][i] <= thr);
            const unsigned long long bits = (bal >> (quad * 16)) & 0xFFFFull;
            if (i < 4) M0 |= bits << (i * 16);
            else       M1 |= bits << ((i - 4) * 16);
        }
        float bs = FLT_MAX; int bk = 0x7FFFFFFF;
        while (__any((M0 | M1) != 0ull)) {
            int myt = -1;                          // quad-uniform next group, ascending
            if (M0) { myt = __ffsll(M0) - 1; M0 &= M0 - 1; }
            else if (M1) { myt = 64 + __ffsll(M1) - 1; M1 &= M1 - 1; }
            if (myt >= 0) {
                const int kg = myt * 16 + ql;
                const float e2k = e2[kg];          // hoisted off the chain's tail
                // permuted layout: quad reads 256 B contiguous per c4 step
                const float4* gp = reinterpret_cast<const float4*>(embp)
                                   + (size_t)myt * 1024 + ql;
                // 8x8 segmented prefetch pipeline: pre[] holds seg s+1's loads
                // in flight while seg s's np-exact fmaf chain retires.
                float4 pre[8];
                #pragma unroll
                for (int s8 = 0; s8 < 8; ++s8) pre[s8] = gp[s8 * 16];
                float dot = 0.f;                   // np-exact ascending-c fmaf chain
                #pragma unroll
                for (int seg = 0; seg < 8; ++seg) {
                    float4 cur[8];
                    #pragma unroll
                    for (int s8 = 0; s8 < 8; ++s8) cur[s8] = pre[s8];
                    if (seg < 7) {
                        #pragma unroll
                        for (int s8 = 0; s8 < 8; ++s8)
                            pre[s8] = gp[(seg + 1) * 128 + s8 * 16];
                    }
                    #pragma unroll
                    for (int s8 = 0; s8 < 8; ++s8) {
                        const int c4 = seg * 8 + s8;
                        const float4 zv = *reinterpret_cast<const float4*>(zr + c4 * 4);
                        dot = fmaf(zv.x, cur[s8].x, dot);
                        dot = fmaf(zv.y, cur[s8].y, dot);
                        dot = fmaf(zv.z, cur[s8].z, dot);
                        dot = fmaf(zv.w, cur[s8].w, dot);
                    }
                }
                const float A = __fadd_rn(z2n, e2k);
                const float s = __fsub_rn(A, __fmul_rn(2.f, dot));
                if (s < bs || (s == bs && kg < bk)) { bs = s; bk = kg; }
            }
        }
        #pragma unroll
        for (int off = 1; off < 16; off <<= 1) {   // lex-min within quad = np.argmin
            const float os = __shfl_xor(bs, off);
            const int ok = __shfl_xor(bk, off);
            if (os < bs || (os == bs && ok < bk)) { bs = os; bk = ok; }
        }
        // gather z_q row (out[n][c] = emb[idx[n]][c]) + loss, float4 per quad-lane
        const float* eq = emb + (size_t)bk * DIM;
        float* op = outf + (size_t)n * DIM;
        #pragma unroll
        for (int jj = 0; jj < 4; ++jj) {
            const int c = (jj * 16 + ql) * 4;
            const float4 q4 = *reinterpret_cast<const float4*>(eq + c);
            f32x4 q; q[0] = q4.x; q[1] = q4.y; q[2] = q4.z; q[3] = q4.w;
            nt_store4(op + c, q);
            float d;
            d = q4.x - zr[c + 0]; lossacc = fmaf(d, d, lossacc);
            d = q4.y - zr[c + 1]; lossacc = fmaf(d, d, lossacc);
            d = q4.z - zr[c + 2]; lossacc = fmaf(d, d, lossacc);
            d = q4.w - zr[c + 3]; lossacc = fmaf(d, d, lossacc);
        }
        if (ql == 0) out_idx[n] = (float)bk;
    }
    #pragma unroll
    for (int off = 1; off < 64; off <<= 1) lossacc += __shfl_xor(lossacc, off);
    if (lane == 0) atomicAdd(&partial[blockIdx.x & 63], lossacc);
}

__global__ void finalize_kernel(const float* __restrict__ partial, float* __restrict__ out_loss) {
    float v = partial[threadIdx.x];          // 64 threads
    #pragma unroll
    for (int off = 1; off < 64; off <<= 1) v += __shfl_xor(v, off);
    if (threadIdx.x == 0)
        *out_loss = v * 1.25f / (float)N_ELEM;   // (1+BETA)*mean
}

extern "C" void kernel_launch(void* const* d_in, const int* in_sizes, int n_in,
                              void* d_out, int out_size, void* d_ws, size_t ws_size,
                              hipStream_t stream) {
    const float* z = (const float*)d_in[0];
    const float* emb = (const float*)d_in[1];
    char* ws = (char*)d_ws;
    float* partial = (float*)(ws + WS_PARTIAL);
    float* e2 = (float*)(ws + WS_E2);
    ushort_t* eb = (ushort_t*)(ws + WS_EB);
    ushort_t* zt = (ushort_t*)(ws + WS_ZT);
    float* embp = (float*)(ws + WS_EMBP);    // overlays zt (dead after screen)
    float* tmin = (float*)(ws + WS_TMIN);
    float* outf = (float*)d_out;
    float* out_loss = outf + N_ELEM;
    float* out_idx = outf + N_ELEM + 1;

    conv_emb_kernel<<<512, 256, 0, stream>>>(emb, eb);
    e2p_kernel<<<N_CODES / 256, 256, 0, stream>>>(emb, e2, partial);
    transpose_kernel<<<2048, 256, 0, stream>>>(z, zt);
    screen_kernel<<<2048, 256, 0, stream>>>(zt, eb, e2, tmin);
    perm_emb_kernel<<<512, 256, 0, stream>>>(emb, embp);   // after screen: reuses zt region
    exact_kernel<<<N_PTS / 32, 256, 0, stream>>>(z, emb, embp, e2, tmin, outf, out_idx, partial);
    finalize_kernel<<<1, 64, 0, stream>>>(partial, out_loss);
}